// Round 7
// baseline (41.470 us; speedup 1.0000x reference)
//
#include <hip/hip_runtime.h>
#include <math.h>

#define NBINS   100
#define NTYPES  6
#define NHIST   (NTYPES * NBINS)   // 600
#define NATOMS  1024
#define GPB     128                // blocks per frame
#define IPB     (NATOMS / GPB)     // 8 i-atoms per block
#define T1      1024
#define NW1     (T1 / 64)          // 16 waves
#define R0f     0.5f
#define R1f     7.5f

// ---------------- kernel 1: per-block partial pair histograms ----------------
// grid = (GPB, B); block = T1.
// partial layout: [B][NHIST][GPB] float (transposed) — block blk writes
// partial[frame][r][blk] unconditionally: no zero-init, no global atomics,
// and the reduce kernel reads each entry's 128 partials CONTIGUOUSLY.
// Ordered pairs (i != j): doubles every count uniformly per (frame,type) row;
// counts / counts.sum() is invariant to that, so the result matches the
// reference's triangular enumeration exactly.
__global__ __launch_bounds__(T1)
void pdf_pairs_kernel(const float* __restrict__ xyz,
                      const int*   __restrict__ numbers,
                      const float* __restrict__ bins,
                      const float* __restrict__ cell,
                      float* __restrict__ partial) {
    __shared__ float shist[NW1][NHIST];   // per-wave hists: 38.4 KB

    const int frame = blockIdx.y;
    const int tid   = threadIdx.x;
    const int wave  = tid >> 6;

    for (int k = tid; k < NW1 * NHIST; k += T1)
        ((float*)shist)[k] = 0.0f;

    const float cx = cell[0], cy = cell[1], cz = cell[2];
    const float icx = 1.0f / cx, icy = 1.0f / cy, icz = 1.0f / cz;
    const float w     = bins[1] - bins[0];
    const float sigma = w * 0.3989422804014327f;              // w / sqrt(2*pi)
    // exp(-0.5*(d/sigma)^2) == exp2(negc * d^2)
    const float negc  = -(0.5f / (sigma * sigma)) * 1.4426950408889634f;
    const float invw  = 1.0f / w;
    const float w05   = 0.5f * w;
    const float c1    = -2.0f * negc * w;                     // coeff of m*base
    const float c2    = negc * w * w;                         // coeff of m^2

    __syncthreads();

    const float* fx = xyz + (size_t)frame * NATOMS * 3;
    const int i0 = blockIdx.x * IPB;

    // i-side atoms: uniform across block -> broadcast loads
    float ix[IPB], iy[IPB], iz[IPB];
    int   it[IPB];
    #pragma unroll
    for (int a = 0; a < IPB; ++a) {
        ix[a] = fx[(i0 + a) * 3 + 0];
        iy[a] = fx[(i0 + a) * 3 + 1];
        iz[a] = fx[(i0 + a) * 3 + 2];
        const int z = numbers[i0 + a];
        it[a] = (z > 21) ? ((z > 55) ? 2 : 1) : 0;   // rank in sorted {8,22,56}
    }

    // j-side: one coalesced sweep (T1 == NATOMS)
    const int j = tid;
    const float jx = fx[j * 3 + 0];
    const float jy = fx[j * 3 + 1];
    const float jz = fx[j * 3 + 2];
    const int  zj = numbers[j];
    const int  jt = (zj > 21) ? ((zj > 55) ? 2 : 1) : 0;

    float* wh = shist[wave];

    #pragma unroll
    for (int a = 0; a < IPB; ++a) {
        float dx = ix[a] - jx;
        float dy = iy[a] - jy;
        float dz = iz[a] - jz;
        // minimum image (diagonal cell): d - cell*rint(d/cell)
        dx -= cx * rintf(dx * icx);
        dy -= cy * rintf(dy * icy);
        dz -= cz * rintf(dz * icz);
        const float dist = sqrtf(dx * dx + dy * dy + dz * dz);
        // i==j -> dist=0 -> kc=-8 -> whole window out of range -> no-op.
        // dist >= cutoff(8.0) -> kc >= 107 -> k > 99 -> no-op.

        const int lo = min(it[a], jt);
        const int hi = max(it[a], jt);
        const int t  = 2 * lo - (lo >> 1) + hi;   // == lo*(5-lo)/2 + hi
        float* th = wh + t * NBINS;

        const float t0 = dist - R0f;
        const float kf = floorf(t0 * invw);
        const int   kc = (int)kf;
        // base = dist - center(kc);  arg(m) = negc*(base - m*w)^2
        //       = A + m*B + m^2*c2,  m = k - kc in [-2,2]
        const float base = (t0 - w05) - kf * w;
        const float A = negc * base * base;
        const float Bq = c1 * base;

        // fixed 5-wide window (+/-2 bins; edge >= 6.3 sigma, tail <= 2e-9),
        // fully unrolled, adds predicated — no divergent loop bounds
        #pragma unroll
        for (int u = 0; u < 5; ++u) {
            const float m = (float)(u - 2);
            const int   k = kc + (u - 2);
            const float arg = (A + m * m * c2) + m * Bq;
            const float v = __builtin_amdgcn_exp2f(arg);   // v_exp_f32
            if ((unsigned)k < (unsigned)NBINS)
                atomicAdd(&th[k], v);                      // native ds_add_f32
        }
    }
    __syncthreads();

    // combine per-wave hists -> transposed partial slice (plain stores)
    float* gp = partial + (size_t)frame * NHIST * GPB + blockIdx.x;
    for (int r = tid; r < NHIST; r += T1) {
        float v = 0.0f;
        #pragma unroll
        for (int wv = 0; wv < NW1; ++wv) v += shist[wv][r];
        gp[(size_t)r * GPB] = v;
    }
}

// ---------------- kernel 2: sum partials, normalize, combine ----------------
// single block, 1024 threads; partial is [B][NHIST][GPB], each entry's 128
// partials contiguous -> float4 streaming loads, all independent.
__global__ __launch_bounds__(1024)
void pdf_reduce_kernel(const float* __restrict__ partial,
                       const float* __restrict__ bins,
                       float* __restrict__ out,
                       int out_size, int nframes) {
    __shared__ float h[8 * NHIST];      // supports B <= 8
    __shared__ float ssum[8 * NTYPES];
    const int tid = threadIdx.x;

    for (int e = tid; e < nframes * NHIST; e += 1024) {
        const float4* src = reinterpret_cast<const float4*>(partial + (size_t)e * GPB);
        float s0 = 0.0f, s1 = 0.0f, s2 = 0.0f, s3 = 0.0f;
        #pragma unroll
        for (int g = 0; g < GPB / 4; ++g) {
            const float4 v = src[g];
            s0 += v.x; s1 += v.y; s2 += v.z; s3 += v.w;
        }
        h[e] = (s0 + s1) + (s2 + s3);
    }
    __syncthreads();

    // per-(frame,type) row sums
    if (tid < nframes * NTYPES) {
        float s = 0.0f;
        const float* row = h + tid * NBINS;
        for (int k = 0; k < NBINS; ++k) s += row[k];
        ssum[tid] = s;
    }
    __syncthreads();

    const float PI = 3.14159265358979323846f;
    const float V = (4.0f / 3.0f) * PI * R1f * R1f * R1f;
    const float coeffs[NTYPES] = {23.04f, 42.24f, 107.52f, 19.36f, 98.56f, 125.44f};

    if (tid < NBINS) {
        const float b0 = bins[tid], b1 = bins[tid + 1];
        const float volb = (4.0f * PI / 3.0f) * (b1 * b1 * b1 - b0 * b0 * b0);
        const float scale = V / volb;
        float acc = 0.0f;
        for (int b = 0; b < nframes; ++b) {
            float facc = 0.0f;
            for (int t = 0; t < NTYPES; ++t) {
                const float cn = h[(b * NTYPES + t) * NBINS + tid]
                                 / ssum[b * NTYPES + t];
                facc += coeffs[t] * (cn * scale - 1.0f);
            }
            acc += facc;
        }
        out[tid] = acc / (float)nframes / 416.16f;
    }

    // second tuple output: bins, copied verbatim (if the harness expects it)
    if (out_size >= NBINS + (NBINS + 1)) {
        if (tid >= NBINS && tid < NBINS + (NBINS + 1)) {
            out[tid] = bins[tid - NBINS];
        }
    }
}

extern "C" void kernel_launch(void* const* d_in, const int* in_sizes, int n_in,
                              void* d_out, int out_size, void* d_ws, size_t ws_size,
                              hipStream_t stream) {
    const float* xyz     = (const float*)d_in[0];
    const int*   numbers = (const int*)d_in[1];
    const float* bins    = (const float*)d_in[2];
    const float* cell    = (const float*)d_in[3];
    float* out     = (float*)d_out;
    float* partial = (float*)d_ws;

    const int B = in_sizes[0] / (NATOMS * 3);

    dim3 grid(GPB, B);
    pdf_pairs_kernel<<<grid, T1, 0, stream>>>(xyz, numbers, bins, cell, partial);
    pdf_reduce_kernel<<<1, 1024, 0, stream>>>(partial, bins, out, out_size, B);
}

// Round 8
// 25.070 us; speedup vs baseline: 1.6542x; 1.6542x over previous
//
#include <hip/hip_runtime.h>
#include <math.h>

#define NBINS   100
#define NTYPES  6
#define NHIST   (NTYPES * NBINS)   // 600
#define NATOMS  1024
#define GPB     128                // blocks per frame
#define IPB     (NATOMS / GPB)     // 8 i-atoms per block
#define T1      1024
#define NW1     (T1 / 64)          // 16 waves
#define R0f     0.5f
#define R1f     7.5f

// ---------------- kernel 1: per-block partial pair histograms ----------------
// grid = (GPB, B); block = T1.
// partial layout: [B][GPB][NHIST] float — each block WRITES its full slice
// with contiguous coalesced stores (no zero-init, no global atomics).
// Ordered pairs (i != j): doubles every count uniformly per (frame,type) row;
// counts / counts.sum() is invariant to that, so the result matches the
// reference's triangular enumeration exactly.
__global__ __launch_bounds__(T1)
void pdf_pairs_kernel(const float* __restrict__ xyz,
                      const int*   __restrict__ numbers,
                      const float* __restrict__ bins,
                      const float* __restrict__ cell,
                      float* __restrict__ partial) {
    __shared__ float shist[NW1][NHIST];   // per-wave hists: 38.4 KB

    const int frame = blockIdx.y;
    const int tid   = threadIdx.x;
    const int wave  = tid >> 6;

    for (int k = tid; k < NW1 * NHIST; k += T1)
        ((float*)shist)[k] = 0.0f;

    const float cx = cell[0], cy = cell[1], cz = cell[2];
    const float icx = 1.0f / cx, icy = 1.0f / cy, icz = 1.0f / cz;
    const float w     = bins[1] - bins[0];
    const float sigma = w * 0.3989422804014327f;              // w / sqrt(2*pi)
    // exp(-0.5*(d/sigma)^2) == exp2(negc * d^2)
    const float negc  = -(0.5f / (sigma * sigma)) * 1.4426950408889634f;
    const float invw  = 1.0f / w;
    const float w05   = 0.5f * w;
    const float c1    = -2.0f * negc * w;                     // coeff of m*base
    const float c2    = negc * w * w;                         // coeff of m^2

    __syncthreads();

    const float* fx = xyz + (size_t)frame * NATOMS * 3;
    const int i0 = blockIdx.x * IPB;

    // i-side atoms: uniform across block -> broadcast loads
    float ix[IPB], iy[IPB], iz[IPB];
    int   it[IPB];
    #pragma unroll
    for (int a = 0; a < IPB; ++a) {
        ix[a] = fx[(i0 + a) * 3 + 0];
        iy[a] = fx[(i0 + a) * 3 + 1];
        iz[a] = fx[(i0 + a) * 3 + 2];
        const int z = numbers[i0 + a];
        it[a] = (z > 21) ? ((z > 55) ? 2 : 1) : 0;   // rank in sorted {8,22,56}
    }

    // j-side: one coalesced sweep (T1 == NATOMS)
    const int j = tid;
    const float jx = fx[j * 3 + 0];
    const float jy = fx[j * 3 + 1];
    const float jz = fx[j * 3 + 2];
    const int  zj = numbers[j];
    const int  jt = (zj > 21) ? ((zj > 55) ? 2 : 1) : 0;

    float* wh = shist[wave];

    #pragma unroll
    for (int a = 0; a < IPB; ++a) {
        float dx = ix[a] - jx;
        float dy = iy[a] - jy;
        float dz = iz[a] - jz;
        // minimum image (diagonal cell): d - cell*rint(d/cell)
        dx -= cx * rintf(dx * icx);
        dy -= cy * rintf(dy * icy);
        dz -= cz * rintf(dz * icz);
        const float dist = sqrtf(dx * dx + dy * dy + dz * dz);
        // i==j -> dist=0 -> kc=-8 -> whole window out of range -> no-op.
        // dist >= cutoff(8.0) -> kc >= 107 -> k > 99 -> no-op.

        const int lo = min(it[a], jt);
        const int hi = max(it[a], jt);
        const int t  = 2 * lo - (lo >> 1) + hi;   // == lo*(5-lo)/2 + hi
        float* th = wh + t * NBINS;

        const float t0 = dist - R0f;
        const float kf = floorf(t0 * invw);
        const int   kc = (int)kf;
        // base = dist - center(kc);  arg(m) = negc*(base - m*w)^2
        //       = A + m*Bq + m^2*c2,  m = k - kc in [-2,2]
        const float base = (t0 - w05) - kf * w;
        const float A  = negc * base * base;
        const float Bq = c1 * base;

        // fixed 5-wide window (+/-2 bins; edge >= 6.3 sigma, tail <= 2e-9),
        // fully unrolled, adds predicated — no divergent loop bounds
        #pragma unroll
        for (int u = 0; u < 5; ++u) {
            const float m = (float)(u - 2);
            const int   k = kc + (u - 2);
            const float arg = (A + m * m * c2) + m * Bq;
            const float v = __builtin_amdgcn_exp2f(arg);   // v_exp_f32
            if ((unsigned)k < (unsigned)NBINS)
                atomicAdd(&th[k], v);                      // native ds_add_f32
        }
    }
    __syncthreads();

    // combine per-wave hists -> this block's private slice (coalesced stores)
    float* gp = partial + ((size_t)frame * GPB + blockIdx.x) * NHIST;
    for (int k = tid; k < NHIST; k += T1) {
        float v = 0.0f;
        #pragma unroll
        for (int wv = 0; wv < NW1; ++wv) v += shist[wv][k];
        gp[k] = v;
    }
}

// ---------------- kernel 2: sum partials, normalize, combine ----------------
// single block, 1024 threads. partial is [B][GPB][NHIST]; threads read float4
// ALONG r (consecutive threads -> consecutive 16B -> coalesced), with the
// g-loop split into two halves across the block for 2x latency hiding.
__global__ __launch_bounds__(1024)
void pdf_reduce_kernel(const float* __restrict__ partial,
                       const float* __restrict__ bins,
                       float* __restrict__ out,
                       int out_size, int nframes) {
    __shared__ float4 hp[2][512];       // half-sums, quad-indexed
    __shared__ float  h[8 * NHIST];     // supports B <= 8
    __shared__ float  ssum[8 * NTYPES];
    const int tid = threadIdx.x;

    const int NQ   = nframes * NHIST / 4;   // quads over [B][NHIST] (B=2 -> 300)
    const int half = tid >> 9;              // 0 or 1
    const int lane = tid & 511;

    if (lane < NQ) {
        const int e4 = lane;
        const int b  = (e4 * 4) / NHIST;
        const int r  = (e4 * 4) - b * NHIST;
        const char* base = (const char*)(partial + ((size_t)b * GPB) * NHIST + r);
        float s0 = 0.0f, s1 = 0.0f, s2 = 0.0f, s3 = 0.0f;
        const int g0 = half * (GPB / 2);
        #pragma unroll 8
        for (int g = 0; g < GPB / 2; ++g) {
            const float4 v = *(const float4*)(base + (size_t)(g0 + g) * (NHIST * 4));
            s0 += v.x; s1 += v.y; s2 += v.z; s3 += v.w;
        }
        hp[half][e4] = make_float4(s0, s1, s2, s3);
    }
    __syncthreads();

    if (tid < NQ) {
        const float4 a = hp[0][tid];
        const float4 b4 = hp[1][tid];
        h[tid * 4 + 0] = a.x + b4.x;
        h[tid * 4 + 1] = a.y + b4.y;
        h[tid * 4 + 2] = a.z + b4.z;
        h[tid * 4 + 3] = a.w + b4.w;
    }
    __syncthreads();

    // per-(frame,type) row sums
    if (tid < nframes * NTYPES) {
        float s = 0.0f;
        const float* row = h + tid * NBINS;
        for (int k = 0; k < NBINS; ++k) s += row[k];
        ssum[tid] = s;
    }
    __syncthreads();

    const float PI = 3.14159265358979323846f;
    const float V = (4.0f / 3.0f) * PI * R1f * R1f * R1f;
    const float coeffs[NTYPES] = {23.04f, 42.24f, 107.52f, 19.36f, 98.56f, 125.44f};

    if (tid < NBINS) {
        const float b0 = bins[tid], b1 = bins[tid + 1];
        const float volb = (4.0f * PI / 3.0f) * (b1 * b1 * b1 - b0 * b0 * b0);
        const float scale = V / volb;
        float acc = 0.0f;
        for (int b = 0; b < nframes; ++b) {
            float facc = 0.0f;
            for (int t = 0; t < NTYPES; ++t) {
                const float cn = h[(b * NTYPES + t) * NBINS + tid]
                                 / ssum[b * NTYPES + t];
                facc += coeffs[t] * (cn * scale - 1.0f);
            }
            acc += facc;
        }
        out[tid] = acc / (float)nframes / 416.16f;
    }

    // second tuple output: bins, copied verbatim (if the harness expects it)
    if (out_size >= NBINS + (NBINS + 1)) {
        if (tid >= NBINS && tid < NBINS + (NBINS + 1)) {
            out[tid] = bins[tid - NBINS];
        }
    }
}

extern "C" void kernel_launch(void* const* d_in, const int* in_sizes, int n_in,
                              void* d_out, int out_size, void* d_ws, size_t ws_size,
                              hipStream_t stream) {
    const float* xyz     = (const float*)d_in[0];
    const int*   numbers = (const int*)d_in[1];
    const float* bins    = (const float*)d_in[2];
    const float* cell    = (const float*)d_in[3];
    float* out     = (float*)d_out;
    float* partial = (float*)d_ws;

    const int B = in_sizes[0] / (NATOMS * 3);

    dim3 grid(GPB, B);
    pdf_pairs_kernel<<<grid, T1, 0, stream>>>(xyz, numbers, bins, cell, partial);
    pdf_reduce_kernel<<<1, 1024, 0, stream>>>(partial, bins, out, out_size, B);
}